// Round 1
// baseline (469.802 us; speedup 1.0000x reference)
//
#include <hip/hip_runtime.h>
#include <stdint.h>

#define T_TOK 2048
#define KTOP  2
#define NEXP  8
#define HDIM  1024
#define IDIM  2816

#define BM        256
#define MAX_TILES 24
#define NPAIR     (T_TOK * KTOP)     // 4096
#define NPAIR_PAD (NPAIR + BM)       // 4352

#define BN2  128   // gate/up N tile
#define BK2  32
#define BKp2 40    // 32 + 8 pad

#define BN3  64    // down N tile
#define BK3  64
#define BKp3 72    // 64 + 8 pad

typedef __attribute__((ext_vector_type(8))) short short8;
typedef __attribute__((ext_vector_type(4))) float floatx4;

__device__ __forceinline__ unsigned short f2bf(float f) {
  unsigned int u = __float_as_uint(f);
  u += 0x7fffu + ((u >> 16) & 1u);   // round-to-nearest-even
  return (unsigned short)(u >> 16);
}

// ---------------------------------------------------------------- setup ----
__global__ void setup_kernel(const int* __restrict__ idx,
                             const float* __restrict__ vals,
                             int* __restrict__ hdr,
                             int* __restrict__ stok,
                             float* __restrict__ sw) {
  __shared__ int cnt[NEXP];
  __shared__ int off[NEXP];
  int tid = threadIdx.x;
  if (tid < NEXP) cnt[tid] = 0;
  __syncthreads();
  for (int p = tid; p < NPAIR; p += blockDim.x) atomicAdd(&cnt[idx[p]], 1);
  __syncthreads();
  if (tid == 0) {
    int s = 0, nt = 0;
    for (int e = 0; e < NEXP; ++e) {
      off[e] = s;
      int n = cnt[e];
      for (int t0 = 0; t0 < n; t0 += BM) {
        hdr[nt] = e;             // expert id
        hdr[32 + nt] = s + t0;   // row0
        hdr[64 + nt] = s + n;    // row_end (segment end)
        nt++;
      }
      s += n;
    }
    for (; nt < MAX_TILES; ++nt) hdr[nt] = -1;
  }
  __syncthreads();
  for (int p = tid; p < NPAIR; p += blockDim.x) {
    int e = idx[p];
    int pos = atomicAdd(&off[e], 1);
    stok[pos] = p / KTOP;
    sw[pos] = vals[p];
  }
}

// --------------------------------------------------------------- gather ----
__global__ void gather_kernel(const float* __restrict__ hidden,
                              const int* __restrict__ stok,
                              unsigned short* __restrict__ Xs) {
  int p = blockIdx.x;
  int t = stok[p];
  const float4* src = reinterpret_cast<const float4*>(hidden + (size_t)t * HDIM);
  float4 v = src[threadIdx.x];
  uint2 q;
  q.x = f2bf(v.x) | ((unsigned)f2bf(v.y) << 16);
  q.y = f2bf(v.z) | ((unsigned)f2bf(v.w) << 16);
  *reinterpret_cast<uint2*>(Xs + (size_t)p * HDIM + threadIdx.x * 4) = q;
}

// -------------------------------------------------- fused gate+up GEMM ----
// C[row, n] for row in expert segment: act = silu(x@wg) * (x@wu) * route_w
__global__ __launch_bounds__(512, 2) void gateup_kernel(
    const unsigned short* __restrict__ Xs, const float* __restrict__ wg,
    const float* __restrict__ wu, const int* __restrict__ hdr,
    const float* __restrict__ sw_g, unsigned short* __restrict__ Act) {
  int by = blockIdx.y;
  int e = hdr[by];
  if (e < 0) return;
  int row0 = hdr[32 + by];
  int row_end = hdr[64 + by];
  int n0 = blockIdx.x * BN2;

  __shared__ __align__(16) unsigned short As[BM * BKp2];
  __shared__ __align__(16) unsigned short Bg[BN2 * BKp2];
  __shared__ __align__(16) unsigned short Bu[BN2 * BKp2];
  __shared__ float sw[BM];

  int tid = threadIdx.x;
  int lane = tid & 63;
  int wave = tid >> 6;
  if (tid < BM) sw[tid] = sw_g[row0 + tid];

  const float* wgb = wg + (size_t)e * HDIM * IDIM;
  const float* wub = wu + (size_t)e * HDIM * IDIM;

  floatx4 accg[4][4], accu[4][4];
  floatx4 z = {0.f, 0.f, 0.f, 0.f};
#pragma unroll
  for (int a = 0; a < 4; ++a)
#pragma unroll
    for (int b = 0; b < 4; ++b) { accg[a][b] = z; accu[a][b] = z; }

  int wm = (wave >> 1) * 64;  // wave row offset   (4 waves in M)
  int wn = (wave & 1) * 64;   // wave col offset   (2 waves in N)

  for (int kb = 0; kb < HDIM; kb += BK2) {
    __syncthreads();
    // stage A: 256x32 bf16 from Xs (already bf16)
#pragma unroll
    for (int it = 0; it < 2; ++it) {
      int cc = wave * 2 + it;               // 0..15
      int m = cc * 16 + (lane >> 2);        // 16 rows per chunk
      int k = (lane & 3) * 8;
      uint4 v = *reinterpret_cast<const uint4*>(Xs + (size_t)(row0 + m) * HDIM + kb + k);
      *reinterpret_cast<uint4*>(&As[m * BKp2 + k]) = v;
    }
    // stage B (gate+up): gather 8 k-rows per lane (coalesced across n), write n-major
#pragma unroll
    for (int it = 0; it < 2; ++it) {
      int cc = wave * 2 + it;               // 0..15
      const float* wb = (cc & 8) ? wub : wgb;
      unsigned short* Bs = (cc & 8) ? Bu : Bg;
      int r = cc & 7;
      int kblk = r >> 1, nh = r & 1;
      int n = nh * 64 + lane;
      int k = kblk * 8;
      const float* src = wb + (size_t)(kb + k) * IDIM + n0 + n;
      uint4 q;
      q.x = f2bf(src[0])        | ((unsigned)f2bf(src[(size_t)IDIM])     << 16);
      q.y = f2bf(src[2 * (size_t)IDIM]) | ((unsigned)f2bf(src[3 * (size_t)IDIM]) << 16);
      q.z = f2bf(src[4 * (size_t)IDIM]) | ((unsigned)f2bf(src[5 * (size_t)IDIM]) << 16);
      q.w = f2bf(src[6 * (size_t)IDIM]) | ((unsigned)f2bf(src[7 * (size_t)IDIM]) << 16);
      *reinterpret_cast<uint4*>(&Bs[n * BKp2 + k]) = q;
    }
    __syncthreads();

    int krd = (lane >> 4) * 8;
    short8 af[4], bgf[4], buf_[4];
#pragma unroll
    for (int tm = 0; tm < 4; ++tm)
      af[tm] = *reinterpret_cast<const short8*>(&As[(wm + tm * 16 + (lane & 15)) * BKp2 + krd]);
#pragma unroll
    for (int tn = 0; tn < 4; ++tn) {
      bgf[tn] = *reinterpret_cast<const short8*>(&Bg[(wn + tn * 16 + (lane & 15)) * BKp2 + krd]);
      buf_[tn] = *reinterpret_cast<const short8*>(&Bu[(wn + tn * 16 + (lane & 15)) * BKp2 + krd]);
    }
#pragma unroll
    for (int tm = 0; tm < 4; ++tm)
#pragma unroll
      for (int tn = 0; tn < 4; ++tn) {
        accg[tm][tn] = __builtin_amdgcn_mfma_f32_16x16x32_bf16(af[tm], bgf[tn], accg[tm][tn], 0, 0, 0);
        accu[tm][tn] = __builtin_amdgcn_mfma_f32_16x16x32_bf16(af[tm], buf_[tn], accu[tm][tn], 0, 0, 0);
      }
  }

  int rowlim = row_end - row0;
#pragma unroll
  for (int tm = 0; tm < 4; ++tm)
#pragma unroll
    for (int tn = 0; tn < 4; ++tn)
#pragma unroll
      for (int r = 0; r < 4; ++r) {
        int rl = wm + tm * 16 + (lane >> 4) * 4 + r;
        if (rl < rowlim) {
          int col = n0 + wn + tn * 16 + (lane & 15);
          float g = accg[tm][tn][r];
          float u = accu[tm][tn][r];
          float s = g / (1.f + __expf(-g));   // silu
          Act[(size_t)(row0 + rl) * IDIM + col] = f2bf(s * u * sw[rl]);
        }
      }
}

// ------------------------------------------------------------ down GEMM ----
__global__ __launch_bounds__(512, 2) void down_kernel(
    const unsigned short* __restrict__ Act, const float* __restrict__ wd,
    const int* __restrict__ hdr, const int* __restrict__ stok,
    float* __restrict__ out) {
  int by = blockIdx.y;
  int e = hdr[by];
  if (e < 0) return;
  int row0 = hdr[32 + by];
  int row_end = hdr[64 + by];
  int n0 = blockIdx.x * BN3;

  __shared__ __align__(16) unsigned short As[BM * BKp3];
  __shared__ __align__(16) unsigned short Bd[BN3 * BKp3];
  __shared__ int stk[BM];

  int tid = threadIdx.x;
  int lane = tid & 63;
  int wave = tid >> 6;
  if (tid < BM) stk[tid] = stok[row0 + tid];

  const float* wdb = wd + (size_t)e * IDIM * HDIM;

  floatx4 acc[4][2];
  floatx4 z = {0.f, 0.f, 0.f, 0.f};
#pragma unroll
  for (int a = 0; a < 4; ++a) { acc[a][0] = z; acc[a][1] = z; }

  int wm = (wave >> 1) * 64;
  int wn = (wave & 1) * 32;

  for (int kb = 0; kb < IDIM; kb += BK3) {   // 44 iters
    __syncthreads();
    // stage A: 256x64 bf16 from Act
#pragma unroll
    for (int it = 0; it < 4; ++it) {
      int cc = wave * 4 + it;               // 0..31
      int m = cc * 8 + (lane >> 3);
      int k = (lane & 7) * 8;
      uint4 v = *reinterpret_cast<const uint4*>(Act + (size_t)(row0 + m) * IDIM + kb + k);
      *reinterpret_cast<uint4*>(&As[m * BKp3 + k]) = v;
    }
    // stage B: 64n x 64k, one chunk per wave
    {
      int n = lane;
      int k = wave * 8;
      const float* src = wdb + (size_t)(kb + k) * HDIM + n0 + n;
      uint4 q;
      q.x = f2bf(src[0])        | ((unsigned)f2bf(src[HDIM])     << 16);
      q.y = f2bf(src[2 * HDIM]) | ((unsigned)f2bf(src[3 * HDIM]) << 16);
      q.z = f2bf(src[4 * HDIM]) | ((unsigned)f2bf(src[5 * HDIM]) << 16);
      q.w = f2bf(src[6 * HDIM]) | ((unsigned)f2bf(src[7 * HDIM]) << 16);
      *reinterpret_cast<uint4*>(&Bd[n * BKp3 + k]) = q;
    }
    __syncthreads();

#pragma unroll
    for (int ks = 0; ks < BK3; ks += 32) {
      int krd = ks + (lane >> 4) * 8;
      short8 af[4], bdf[2];
#pragma unroll
      for (int tm = 0; tm < 4; ++tm)
        af[tm] = *reinterpret_cast<const short8*>(&As[(wm + tm * 16 + (lane & 15)) * BKp3 + krd]);
#pragma unroll
      for (int tn = 0; tn < 2; ++tn)
        bdf[tn] = *reinterpret_cast<const short8*>(&Bd[(wn + tn * 16 + (lane & 15)) * BKp3 + krd]);
#pragma unroll
      for (int tm = 0; tm < 4; ++tm)
#pragma unroll
        for (int tn = 0; tn < 2; ++tn)
          acc[tm][tn] = __builtin_amdgcn_mfma_f32_16x16x32_bf16(af[tm], bdf[tn], acc[tm][tn], 0, 0, 0);
    }
  }

  int rowlim = row_end - row0;
#pragma unroll
  for (int tm = 0; tm < 4; ++tm)
#pragma unroll
    for (int tn = 0; tn < 2; ++tn)
#pragma unroll
      for (int r = 0; r < 4; ++r) {
        int rl = wm + tm * 16 + (lane >> 4) * 4 + r;
        if (rl < rowlim) {
          int col = n0 + wn + tn * 16 + (lane & 15);
          int t = stk[rl];
          unsafeAtomicAdd(&out[(size_t)t * HDIM + col], acc[tm][tn][r]);
        }
      }
}

// ---------------------------------------------------------------- launch ----
extern "C" void kernel_launch(void* const* d_in, const int* in_sizes, int n_in,
                              void* d_out, int out_size, void* d_ws, size_t ws_size,
                              hipStream_t stream) {
  const float* hidden = (const float*)d_in[0];
  const int* idx = (const int*)d_in[1];
  const float* vals = (const float*)d_in[2];
  const float* wg = (const float*)d_in[3];
  const float* wu = (const float*)d_in[4];
  const float* wd = (const float*)d_in[5];
  float* out = (float*)d_out;

  char* ws = (char*)d_ws;
  int* hdr = (int*)ws;                                     // 4 KB header
  int* stok = (int*)(ws + 4096);                           // 4352 ints
  float* sw = (float*)(ws + 4096 + NPAIR_PAD * 4);         // 4352 floats
  unsigned short* Xs = (unsigned short*)(ws + 65536);      // [4352,1024] bf16
  unsigned short* Act = (unsigned short*)(ws + 65536 + (size_t)NPAIR_PAD * HDIM * 2); // [4352,2816] bf16

  hipMemsetAsync(d_out, 0, (size_t)out_size * sizeof(float), stream);
  setup_kernel<<<1, 256, 0, stream>>>(idx, vals, hdr, stok, sw);
  gather_kernel<<<NPAIR, 256, 0, stream>>>(hidden, stok, Xs);
  gateup_kernel<<<dim3(IDIM / BN2, MAX_TILES), 512, 0, stream>>>(Xs, wg, wu, hdr, sw, Act);
  down_kernel<<<dim3(HDIM / BN3, MAX_TILES), 512, 0, stream>>>(Act, wd, hdr, stok, out);
}

// Round 2
// 456.336 us; speedup vs baseline: 1.0295x; 1.0295x over previous
//
#include <hip/hip_runtime.h>
#include <stdint.h>

#define T_TOK 2048
#define KTOP  2
#define NEXP  8
#define HDIM  1024
#define IDIM  2816

#define NPAIR 4096

// ---- new path (bf16 transposed weights) ----
#define BM        128
#define MAX_TILES 40
#define NPP       (NPAIR + BM)      // 4224
#define BN2       128               // gate/up N tile
#define BK2       32
#define BN3       64                // down N tile
#define BK3       64

// ---- fallback (round-1) path ----
#define R1BM   256
#define R1T    24
#define R1NPP  (NPAIR + R1BM)       // 4352
#define R1BN2  128
#define R1BK2  32
#define R1BKp2 40
#define R1BN3  64
#define R1BK3  64
#define R1BKp3 72

typedef __attribute__((ext_vector_type(8))) short short8;
typedef __attribute__((ext_vector_type(4))) float floatx4;

__device__ __forceinline__ unsigned short f2bf(float f) {
  unsigned int u = __float_as_uint(f);
  u += 0x7fffu + ((u >> 16) & 1u);   // round-to-nearest-even
  return (unsigned short)(u >> 16);
}

__device__ __forceinline__ void glds16(const unsigned short* g, unsigned short* l) {
  __builtin_amdgcn_global_load_lds(
      (const __attribute__((address_space(1))) unsigned int*)g,
      (__attribute__((address_space(3))) unsigned int*)l, 16, 0, 0);
}

// ---------------------------------------------------------------- setup ----
// hdr[t]=expert, hdr[64+t]=row0, hdr[128+t]=row_end; tiles of `bm` rows.
__global__ void setup_kernel(const int* __restrict__ idx,
                             const float* __restrict__ vals,
                             int* __restrict__ hdr,
                             int* __restrict__ stok,
                             float* __restrict__ sw, int bm) {
  __shared__ int cnt[NEXP];
  __shared__ int off[NEXP];
  int tid = threadIdx.x;
  if (tid < NEXP) cnt[tid] = 0;
  __syncthreads();
  for (int p = tid; p < NPAIR; p += blockDim.x) atomicAdd(&cnt[idx[p]], 1);
  __syncthreads();
  if (tid == 0) {
    int s = 0, nt = 0;
    for (int e = 0; e < NEXP; ++e) {
      off[e] = s;
      int n = cnt[e];
      for (int t0 = 0; t0 < n; t0 += bm) {
        hdr[nt] = e;
        hdr[64 + nt] = s + t0;
        hdr[128 + nt] = s + n;
        nt++;
      }
      s += n;
    }
    for (; nt < 64; ++nt) hdr[nt] = -1;
  }
  __syncthreads();
  for (int p = tid; p < NPAIR; p += blockDim.x) {
    int e = idx[p];
    int pos = atomicAdd(&off[e], 1);
    stok[pos] = p / KTOP;
    sw[pos] = vals[p];
  }
}

// --------------------------------------------------------------- gather ----
__global__ void gather_kernel(const float* __restrict__ hidden,
                              const int* __restrict__ stok,
                              unsigned short* __restrict__ Xs) {
  int p = blockIdx.x;
  int t = stok[p];
  const float4* src = reinterpret_cast<const float4*>(hidden + (size_t)t * HDIM);
  float4 v = src[threadIdx.x];
  uint2 q;
  q.x = f2bf(v.x) | ((unsigned)f2bf(v.y) << 16);
  q.y = f2bf(v.z) | ((unsigned)f2bf(v.w) << 16);
  *reinterpret_cast<uint2*>(Xs + (size_t)p * HDIM + threadIdx.x * 4) = q;
}

// ----------------------------------------------- weight convert+transpose --
// fp32 [e][M][N] -> bf16 [e][N][M].  z (+zoff): 0=wg, 1=wu, 2=wd.
__global__ __launch_bounds__(256) void convert_kernel(
    const float* __restrict__ wg, const float* __restrict__ wu,
    const float* __restrict__ wd, unsigned short* __restrict__ wgT,
    unsigned short* __restrict__ wuT, unsigned short* __restrict__ wdT,
    int zoff) {
  __shared__ float ls[64][65];
  int z = blockIdx.z + zoff;
  int e = blockIdx.y;
  int M = (z == 2) ? IDIM : HDIM;
  int N = (z == 2) ? HDIM : IDIM;
  const float* src = (z == 0 ? wg : z == 1 ? wu : wd) + (size_t)e * M * N;
  unsigned short* dst = (z == 0 ? wgT : z == 1 ? wuT : wdT) + (size_t)e * M * N;
  int ntx = N >> 6;
  int n0 = (blockIdx.x % ntx) << 6;
  int m0 = (blockIdx.x / ntx) << 6;
  int t = threadIdx.x;
  int rr = t >> 4, cc = (t & 15) * 4;
#pragma unroll
  for (int i = 0; i < 4; ++i) {
    int r = rr + i * 16;
    float4 v = *reinterpret_cast<const float4*>(src + (size_t)(m0 + r) * N + n0 + cc);
    ls[r][cc] = v.x; ls[r][cc + 1] = v.y; ls[r][cc + 2] = v.z; ls[r][cc + 3] = v.w;
  }
  __syncthreads();
#pragma unroll
  for (int i = 0; i < 4; ++i) {
    int n = rr + i * 16;
    uint2 q;
    q.x = f2bf(ls[cc][n])     | ((unsigned)f2bf(ls[cc + 1][n]) << 16);
    q.y = f2bf(ls[cc + 2][n]) | ((unsigned)f2bf(ls[cc + 3][n]) << 16);
    *reinterpret_cast<uint2*>(dst + (size_t)(n0 + n) * M + m0 + cc) = q;
  }
}

// -------------------------------------------------- fused gate+up GEMM ----
__global__ __launch_bounds__(256, 2) void gateup_kernel(
    const unsigned short* __restrict__ Xs, const unsigned short* __restrict__ wgT,
    const unsigned short* __restrict__ wuT, const int* __restrict__ hdr,
    const float* __restrict__ sw_g, unsigned short* __restrict__ Act) {
  int by = blockIdx.y;
  int e = hdr[by];
  if (e < 0) return;
  int row0 = hdr[64 + by];
  int rowlim = hdr[128 + by] - row0;
  int n0 = blockIdx.x * BN2;

  __shared__ __align__(16) unsigned short As[BM * BK2];
  __shared__ __align__(16) unsigned short Bg[BN2 * BK2];
  __shared__ __align__(16) unsigned short Bu[BN2 * BK2];
  __shared__ float sw[BM];

  int tid = threadIdx.x, lane = tid & 63, wave = tid >> 6;
  if (tid < BM) sw[tid] = sw_g[row0 + tid];

  const unsigned short* wgb = wgT + (size_t)e * IDIM * HDIM;  // [I][H] bf16
  const unsigned short* wub = wuT + (size_t)e * IDIM * HDIM;

  floatx4 accg[4][4], accu[4][4];
  floatx4 zz = {0.f, 0.f, 0.f, 0.f};
#pragma unroll
  for (int a = 0; a < 4; ++a)
#pragma unroll
    for (int b = 0; b < 4; ++b) { accg[a][b] = zz; accu[a][b] = zz; }

  int wm = (wave >> 1) * 64, wn = (wave & 1) * 64;
  int lr = lane >> 2;            // row within 16-row chunk
  int lk = (lane & 3) * 8;       // elem offset (16 B per lane)
  int fr = lane & 15, fq = (lane >> 4) * 8;

  for (int kb = 0; kb < HDIM; kb += BK2) {
#pragma unroll
    for (int it = 0; it < 2; ++it) {
      int c = wave * 2 + it;     // 0..7, 16 rows each
      glds16(Xs  + (size_t)(row0 + c * 16 + lr) * HDIM + kb + lk, &As[c * 512]);
      glds16(wgb + (size_t)(n0  + c * 16 + lr) * HDIM + kb + lk, &Bg[c * 512]);
      glds16(wub + (size_t)(n0  + c * 16 + lr) * HDIM + kb + lk, &Bu[c * 512]);
    }
    __syncthreads();

    short8 af[4], bg8[4], bu8[4];
#pragma unroll
    for (int x = 0; x < 4; ++x) {
      af[x]  = *reinterpret_cast<const short8*>(&As[(wm + x * 16 + fr) * BK2 + fq]);
      bg8[x] = *reinterpret_cast<const short8*>(&Bg[(wn + x * 16 + fr) * BK2 + fq]);
      bu8[x] = *reinterpret_cast<const short8*>(&Bu[(wn + x * 16 + fr) * BK2 + fq]);
    }
#pragma unroll
    for (int tm = 0; tm < 4; ++tm)
#pragma unroll
      for (int tn = 0; tn < 4; ++tn) {
        accg[tm][tn] = __builtin_amdgcn_mfma_f32_16x16x32_bf16(af[tm], bg8[tn], accg[tm][tn], 0, 0, 0);
        accu[tm][tn] = __builtin_amdgcn_mfma_f32_16x16x32_bf16(af[tm], bu8[tn], accu[tm][tn], 0, 0, 0);
      }
    __syncthreads();
  }

#pragma unroll
  for (int tm = 0; tm < 4; ++tm)
#pragma unroll
    for (int tn = 0; tn < 4; ++tn)
#pragma unroll
      for (int r = 0; r < 4; ++r) {
        int rl = wm + tm * 16 + (lane >> 4) * 4 + r;
        if (rl < rowlim) {
          int col = n0 + wn + tn * 16 + fr;
          float g = accg[tm][tn][r];
          float u = accu[tm][tn][r];
          float s = g / (1.f + __expf(-g));
          Act[(size_t)(row0 + rl) * IDIM + col] = f2bf(s * u * sw[rl]);
        }
      }
}

// ------------------------------------------------------------ down GEMM ----
__global__ __launch_bounds__(256, 3) void down_kernel(
    const unsigned short* __restrict__ Act, const unsigned short* __restrict__ wdT,
    const int* __restrict__ hdr, const int* __restrict__ stok,
    float* __restrict__ out) {
  int by = blockIdx.y;
  int e = hdr[by];
  if (e < 0) return;
  int row0 = hdr[64 + by];
  int rowlim = hdr[128 + by] - row0;
  int n0 = blockIdx.x * BN3;

  __shared__ __align__(16) unsigned short As[BM * BK3];   // 128 x 64
  __shared__ __align__(16) unsigned short Bd[BN3 * BK3];  // 64 x 64
  __shared__ int stk[BM];

  int tid = threadIdx.x, lane = tid & 63, wave = tid >> 6;
  if (tid < BM) stk[tid] = stok[row0 + tid];

  const unsigned short* wdb = wdT + (size_t)e * HDIM * IDIM;  // [H][I] bf16

  floatx4 acc[4][2];
  floatx4 zz = {0.f, 0.f, 0.f, 0.f};
#pragma unroll
  for (int a = 0; a < 4; ++a) { acc[a][0] = zz; acc[a][1] = zz; }

  int wm = (wave >> 1) * 64, wn = (wave & 1) * 32;
  int lr8 = lane >> 3;           // row within 8-row chunk (128 B rows)
  int lk8 = (lane & 7) * 8;      // elem offset
  int fr = lane & 15, fq = (lane >> 4) * 8;

  for (int kb = 0; kb < IDIM; kb += BK3) {   // 44 iters
#pragma unroll
    for (int it = 0; it < 4; ++it) {
      int c = wave * 4 + it;     // 0..15, 8 rows each
      glds16(Act + (size_t)(row0 + c * 8 + lr8) * IDIM + kb + lk8, &As[c * 512]);
    }
#pragma unroll
    for (int it = 0; it < 2; ++it) {
      int c = wave * 2 + it;     // 0..7, 8 rows each
      glds16(wdb + (size_t)(n0 + c * 8 + lr8) * IDIM + kb + lk8, &Bd[c * 512]);
    }
    __syncthreads();

#pragma unroll
    for (int ks = 0; ks < BK3; ks += 32) {
      short8 af[4], bd8[2];
#pragma unroll
      for (int x = 0; x < 4; ++x)
        af[x] = *reinterpret_cast<const short8*>(&As[(wm + x * 16 + fr) * BK3 + ks + fq]);
#pragma unroll
      for (int x = 0; x < 2; ++x)
        bd8[x] = *reinterpret_cast<const short8*>(&Bd[(wn + x * 16 + fr) * BK3 + ks + fq]);
#pragma unroll
      for (int tm = 0; tm < 4; ++tm)
#pragma unroll
        for (int tn = 0; tn < 2; ++tn)
          acc[tm][tn] = __builtin_amdgcn_mfma_f32_16x16x32_bf16(af[tm], bd8[tn], acc[tm][tn], 0, 0, 0);
    }
    __syncthreads();
  }

#pragma unroll
  for (int tm = 0; tm < 4; ++tm)
#pragma unroll
    for (int tn = 0; tn < 2; ++tn)
#pragma unroll
      for (int r = 0; r < 4; ++r) {
        int rl = wm + tm * 16 + (lane >> 4) * 4 + r;
        if (rl < rowlim) {
          int col = n0 + wn + tn * 16 + fr;
          unsafeAtomicAdd(&out[(size_t)stk[rl] * HDIM + col], acc[tm][tn][r]);
        }
      }
}

// ======================== round-1 fallback kernels =========================
__global__ __launch_bounds__(512, 2) void gateup_fb(
    const unsigned short* __restrict__ Xs, const float* __restrict__ wg,
    const float* __restrict__ wu, const int* __restrict__ hdr,
    const float* __restrict__ sw_g, unsigned short* __restrict__ Act) {
  int by = blockIdx.y;
  int e = hdr[by];
  if (e < 0) return;
  int row0 = hdr[64 + by];
  int row_end = hdr[128 + by];
  int n0 = blockIdx.x * R1BN2;

  __shared__ __align__(16) unsigned short As[R1BM * R1BKp2];
  __shared__ __align__(16) unsigned short Bg[R1BN2 * R1BKp2];
  __shared__ __align__(16) unsigned short Bu[R1BN2 * R1BKp2];
  __shared__ float sw[R1BM];

  int tid = threadIdx.x, lane = tid & 63, wave = tid >> 6;
  if (tid < R1BM) sw[tid] = sw_g[row0 + tid];

  const float* wgb = wg + (size_t)e * HDIM * IDIM;
  const float* wub = wu + (size_t)e * HDIM * IDIM;

  floatx4 accg[4][4], accu[4][4];
  floatx4 zz = {0.f, 0.f, 0.f, 0.f};
#pragma unroll
  for (int a = 0; a < 4; ++a)
#pragma unroll
    for (int b = 0; b < 4; ++b) { accg[a][b] = zz; accu[a][b] = zz; }

  int wm = (wave >> 1) * 64, wn = (wave & 1) * 64;

  for (int kb = 0; kb < HDIM; kb += R1BK2) {
    __syncthreads();
#pragma unroll
    for (int it = 0; it < 2; ++it) {
      int cc = wave * 2 + it;
      int m = cc * 16 + (lane >> 2);
      int k = (lane & 3) * 8;
      uint4 v = *reinterpret_cast<const uint4*>(Xs + (size_t)(row0 + m) * HDIM + kb + k);
      *reinterpret_cast<uint4*>(&As[m * R1BKp2 + k]) = v;
    }
#pragma unroll
    for (int it = 0; it < 2; ++it) {
      int cc = wave * 2 + it;
      const float* wb = (cc & 8) ? wub : wgb;
      unsigned short* Bs = (cc & 8) ? Bu : Bg;
      int r = cc & 7;
      int kblk = r >> 1, nh = r & 1;
      int n = nh * 64 + lane;
      int k = kblk * 8;
      const float* src = wb + (size_t)(kb + k) * IDIM + n0 + n;
      uint4 q;
      q.x = f2bf(src[0])                | ((unsigned)f2bf(src[(size_t)IDIM])     << 16);
      q.y = f2bf(src[2 * (size_t)IDIM]) | ((unsigned)f2bf(src[3 * (size_t)IDIM]) << 16);
      q.z = f2bf(src[4 * (size_t)IDIM]) | ((unsigned)f2bf(src[5 * (size_t)IDIM]) << 16);
      q.w = f2bf(src[6 * (size_t)IDIM]) | ((unsigned)f2bf(src[7 * (size_t)IDIM]) << 16);
      *reinterpret_cast<uint4*>(&Bs[n * R1BKp2 + k]) = q;
    }
    __syncthreads();

    int krd = (lane >> 4) * 8;
    short8 af[4], bgf[4], buf_[4];
#pragma unroll
    for (int tm = 0; tm < 4; ++tm)
      af[tm] = *reinterpret_cast<const short8*>(&As[(wm + tm * 16 + (lane & 15)) * R1BKp2 + krd]);
#pragma unroll
    for (int tn = 0; tn < 4; ++tn) {
      bgf[tn]  = *reinterpret_cast<const short8*>(&Bg[(wn + tn * 16 + (lane & 15)) * R1BKp2 + krd]);
      buf_[tn] = *reinterpret_cast<const short8*>(&Bu[(wn + tn * 16 + (lane & 15)) * R1BKp2 + krd]);
    }
#pragma unroll
    for (int tm = 0; tm < 4; ++tm)
#pragma unroll
      for (int tn = 0; tn < 4; ++tn) {
        accg[tm][tn] = __builtin_amdgcn_mfma_f32_16x16x32_bf16(af[tm], bgf[tn], accg[tm][tn], 0, 0, 0);
        accu[tm][tn] = __builtin_amdgcn_mfma_f32_16x16x32_bf16(af[tm], buf_[tn], accu[tm][tn], 0, 0, 0);
      }
  }

  int rowlim = row_end - row0;
#pragma unroll
  for (int tm = 0; tm < 4; ++tm)
#pragma unroll
    for (int tn = 0; tn < 4; ++tn)
#pragma unroll
      for (int r = 0; r < 4; ++r) {
        int rl = wm + tm * 16 + (lane >> 4) * 4 + r;
        if (rl < rowlim) {
          int col = n0 + wn + tn * 16 + (lane & 15);
          float g = accg[tm][tn][r];
          float u = accu[tm][tn][r];
          float s = g / (1.f + __expf(-g));
          Act[(size_t)(row0 + rl) * IDIM + col] = f2bf(s * u * sw[rl]);
        }
      }
}

__global__ __launch_bounds__(512, 2) void down_fb(
    const unsigned short* __restrict__ Act, const float* __restrict__ wd,
    const int* __restrict__ hdr, const int* __restrict__ stok,
    float* __restrict__ out) {
  int by = blockIdx.y;
  int e = hdr[by];
  if (e < 0) return;
  int row0 = hdr[64 + by];
  int row_end = hdr[128 + by];
  int n0 = blockIdx.x * R1BN3;

  __shared__ __align__(16) unsigned short As[R1BM * R1BKp3];
  __shared__ __align__(16) unsigned short Bd[R1BN3 * R1BKp3];
  __shared__ int stk[R1BM];

  int tid = threadIdx.x, lane = tid & 63, wave = tid >> 6;
  if (tid < R1BM) stk[tid] = stok[row0 + tid];

  const float* wdb = wd + (size_t)e * IDIM * HDIM;

  floatx4 acc[4][2];
  floatx4 zz = {0.f, 0.f, 0.f, 0.f};
#pragma unroll
  for (int a = 0; a < 4; ++a) { acc[a][0] = zz; acc[a][1] = zz; }

  int wm = (wave >> 1) * 64, wn = (wave & 1) * 32;

  for (int kb = 0; kb < IDIM; kb += R1BK3) {
    __syncthreads();
#pragma unroll
    for (int it = 0; it < 4; ++it) {
      int cc = wave * 4 + it;
      int m = cc * 8 + (lane >> 3);
      int k = (lane & 7) * 8;
      uint4 v = *reinterpret_cast<const uint4*>(Act + (size_t)(row0 + m) * IDIM + kb + k);
      *reinterpret_cast<uint4*>(&As[m * R1BKp3 + k]) = v;
    }
    {
      int n = lane;
      int k = wave * 8;
      const float* src = wdb + (size_t)(kb + k) * HDIM + n0 + n;
      uint4 q;
      q.x = f2bf(src[0])        | ((unsigned)f2bf(src[HDIM])     << 16);
      q.y = f2bf(src[2 * HDIM]) | ((unsigned)f2bf(src[3 * HDIM]) << 16);
      q.z = f2bf(src[4 * HDIM]) | ((unsigned)f2bf(src[5 * HDIM]) << 16);
      q.w = f2bf(src[6 * HDIM]) | ((unsigned)f2bf(src[7 * HDIM]) << 16);
      *reinterpret_cast<uint4*>(&Bd[n * R1BKp3 + k]) = q;
    }
    __syncthreads();

#pragma unroll
    for (int ks = 0; ks < R1BK3; ks += 32) {
      int krd = ks + (lane >> 4) * 8;
      short8 af[4], bdf[2];
#pragma unroll
      for (int tm = 0; tm < 4; ++tm)
        af[tm] = *reinterpret_cast<const short8*>(&As[(wm + tm * 16 + (lane & 15)) * R1BKp3 + krd]);
#pragma unroll
      for (int tn = 0; tn < 2; ++tn)
        bdf[tn] = *reinterpret_cast<const short8*>(&Bd[(wn + tn * 16 + (lane & 15)) * R1BKp3 + krd]);
#pragma unroll
      for (int tm = 0; tm < 4; ++tm)
#pragma unroll
        for (int tn = 0; tn < 2; ++tn)
          acc[tm][tn] = __builtin_amdgcn_mfma_f32_16x16x32_bf16(af[tm], bdf[tn], acc[tm][tn], 0, 0, 0);
    }
  }

  int rowlim = row_end - row0;
#pragma unroll
  for (int tm = 0; tm < 4; ++tm)
#pragma unroll
    for (int tn = 0; tn < 2; ++tn)
#pragma unroll
      for (int r = 0; r < 4; ++r) {
        int rl = wm + tm * 16 + (lane >> 4) * 4 + r;
        if (rl < rowlim) {
          int col = n0 + wn + tn * 16 + (lane & 15);
          unsafeAtomicAdd(&out[(size_t)stk[rl] * HDIM + col], acc[tm][tn][r]);
        }
      }
}

// ---------------------------------------------------------------- launch ----
extern "C" void kernel_launch(void* const* d_in, const int* in_sizes, int n_in,
                              void* d_out, int out_size, void* d_ws, size_t ws_size,
                              hipStream_t stream) {
  const float* hidden = (const float*)d_in[0];
  const int* idx = (const int*)d_in[1];
  const float* vals = (const float*)d_in[2];
  const float* wg = (const float*)d_in[3];
  const float* wu = (const float*)d_in[4];
  const float* wd = (const float*)d_in[5];
  float* out = (float*)d_out;
  char* ws = (char*)d_ws;

  hipMemsetAsync(d_out, 0, (size_t)out_size * sizeof(float), stream);

  // new-path workspace layout
  const size_t OFF_STOK = 4096;
  const size_t OFF_SW   = OFF_STOK + (size_t)NPP * 4;
  const size_t OFF_XS   = 65536;
  const size_t OFF_ACT  = OFF_XS + (size_t)NPP * HDIM * 2;
  const size_t OFF_WG   = OFF_ACT + (size_t)NPP * IDIM * 2;
  const size_t WSZ      = (size_t)NEXP * HDIM * IDIM * 2;   // 46.1 MB each
  const size_t OFF_WU   = OFF_WG + WSZ;
  const size_t NEED     = OFF_WU + WSZ;  // wdT aliases wgT (converted post-gateup)

  if (ws_size >= NEED) {
    int* hdr = (int*)ws;
    int* stok = (int*)(ws + OFF_STOK);
    float* sw = (float*)(ws + OFF_SW);
    unsigned short* Xs  = (unsigned short*)(ws + OFF_XS);
    unsigned short* Act = (unsigned short*)(ws + OFF_ACT);
    unsigned short* wgT = (unsigned short*)(ws + OFF_WG);
    unsigned short* wuT = (unsigned short*)(ws + OFF_WU);
    unsigned short* wdT = wgT;  // alias: wd converted after gateup consumed wgT

    setup_kernel<<<1, 256, 0, stream>>>(idx, vals, hdr, stok, sw, BM);
    convert_kernel<<<dim3(704, NEXP, 2), 256, 0, stream>>>(wg, wu, wd, wgT, wuT, wdT, 0);
    gather_kernel<<<NPAIR, 256, 0, stream>>>(hidden, stok, Xs);
    gateup_kernel<<<dim3(IDIM / BN2, MAX_TILES), 256, 0, stream>>>(Xs, wgT, wuT, hdr, sw, Act);
    convert_kernel<<<dim3(704, NEXP, 1), 256, 0, stream>>>(wg, wu, wd, wgT, wuT, wdT, 2);
    down_kernel<<<dim3(HDIM / BN3, MAX_TILES), 256, 0, stream>>>(Act, wdT, hdr, stok, out);
  } else {
    // round-1 fallback: fp32 weights converted inline
    int* hdr = (int*)ws;
    int* stok = (int*)(ws + 4096);
    float* sw = (float*)(ws + 4096 + (size_t)R1NPP * 4);
    unsigned short* Xs  = (unsigned short*)(ws + 65536);
    unsigned short* Act = (unsigned short*)(ws + 65536 + (size_t)R1NPP * HDIM * 2);

    setup_kernel<<<1, 256, 0, stream>>>(idx, vals, hdr, stok, sw, R1BM);
    gather_kernel<<<NPAIR, 256, 0, stream>>>(hidden, stok, Xs);
    gateup_fb<<<dim3(IDIM / R1BN2, R1T), 512, 0, stream>>>(Xs, wg, wu, hdr, sw, Act);
    down_fb<<<dim3(HDIM / R1BN3, R1T), 512, 0, stream>>>(Act, wd, hdr, stok, out);
  }
}

// Round 3
// 452.913 us; speedup vs baseline: 1.0373x; 1.0076x over previous
//
#include <hip/hip_runtime.h>
#include <stdint.h>

#define T_TOK 2048
#define KTOP  2
#define NEXP  8
#define HDIM  1024
#define IDIM  2816

#define NPAIR 4096

// ---- new path (bf16 transposed weights) ----
#define BM        128
#define MAX_TILES 40
#define NPP       (NPAIR + BM)      // 4224
#define BN2       128               // gate/up N tile
#define BK2       32
#define BN3       64                // down N tile
#define BK3       64

// ---- fallback (round-1) path ----
#define R1BM   256
#define R1T    24
#define R1NPP  (NPAIR + R1BM)       // 4352
#define R1BN2  128
#define R1BK2  32
#define R1BKp2 40
#define R1BN3  64
#define R1BK3  64
#define R1BKp3 72

typedef __attribute__((ext_vector_type(8))) short short8;
typedef __attribute__((ext_vector_type(4))) float floatx4;

__device__ __forceinline__ unsigned short f2bf(float f) {
  unsigned int u = __float_as_uint(f);
  u += 0x7fffu + ((u >> 16) & 1u);   // round-to-nearest-even
  return (unsigned short)(u >> 16);
}

__device__ __forceinline__ void glds16(const unsigned short* g, unsigned short* l) {
  __builtin_amdgcn_global_load_lds(
      (const __attribute__((address_space(1))) unsigned int*)g,
      (__attribute__((address_space(3))) unsigned int*)l, 16, 0, 0);
}

// ---------------------------------------------------------------- setup ----
__global__ void setup_kernel(const int* __restrict__ idx,
                             const float* __restrict__ vals,
                             int* __restrict__ hdr,
                             int* __restrict__ stok,
                             float* __restrict__ sw, int bm) {
  __shared__ int cnt[NEXP];
  __shared__ int off[NEXP];
  int tid = threadIdx.x;
  if (tid < NEXP) cnt[tid] = 0;
  __syncthreads();
  for (int p = tid; p < NPAIR; p += blockDim.x) atomicAdd(&cnt[idx[p]], 1);
  __syncthreads();
  if (tid == 0) {
    int s = 0, nt = 0;
    for (int e = 0; e < NEXP; ++e) {
      off[e] = s;
      int n = cnt[e];
      for (int t0 = 0; t0 < n; t0 += bm) {
        hdr[nt] = e;
        hdr[64 + nt] = s + t0;
        hdr[128 + nt] = s + n;
        nt++;
      }
      s += n;
    }
    for (; nt < 64; ++nt) hdr[nt] = -1;
  }
  __syncthreads();
  for (int p = tid; p < NPAIR; p += blockDim.x) {
    int e = idx[p];
    int pos = atomicAdd(&off[e], 1);
    stok[pos] = p / KTOP;
    sw[pos] = vals[p];
  }
}

// --------------------------------------------------------------- gather ----
__global__ void gather_kernel(const float* __restrict__ hidden,
                              const int* __restrict__ stok,
                              unsigned short* __restrict__ Xs) {
  int p = blockIdx.x;
  int t = stok[p];
  const float4* src = reinterpret_cast<const float4*>(hidden + (size_t)t * HDIM);
  float4 v = src[threadIdx.x];
  uint2 q;
  q.x = f2bf(v.x) | ((unsigned)f2bf(v.y) << 16);
  q.y = f2bf(v.z) | ((unsigned)f2bf(v.w) << 16);
  *reinterpret_cast<uint2*>(Xs + (size_t)p * HDIM + threadIdx.x * 4) = q;
}

// ----------------------------------------------- weight convert+transpose --
// fp32 [e][M][N] -> bf16 [e][N][M].  z (+zoff): 0=wg, 1=wu, 2=wd.
__global__ __launch_bounds__(256) void convert_kernel(
    const float* __restrict__ wg, const float* __restrict__ wu,
    const float* __restrict__ wd, unsigned short* __restrict__ wgT,
    unsigned short* __restrict__ wuT, unsigned short* __restrict__ wdT,
    int zoff) {
  __shared__ float ls[64][65];
  int z = blockIdx.z + zoff;
  int e = blockIdx.y;
  int M = (z == 2) ? IDIM : HDIM;
  int N = (z == 2) ? HDIM : IDIM;
  const float* src = (z == 0 ? wg : z == 1 ? wu : wd) + (size_t)e * M * N;
  unsigned short* dst = (z == 0 ? wgT : z == 1 ? wuT : wdT) + (size_t)e * M * N;
  int ntx = N >> 6;
  int n0 = (blockIdx.x % ntx) << 6;
  int m0 = (blockIdx.x / ntx) << 6;
  int t = threadIdx.x;
  int rr = t >> 4, cc = (t & 15) * 4;
#pragma unroll
  for (int i = 0; i < 4; ++i) {
    int r = rr + i * 16;
    float4 v = *reinterpret_cast<const float4*>(src + (size_t)(m0 + r) * N + n0 + cc);
    ls[r][cc] = v.x; ls[r][cc + 1] = v.y; ls[r][cc + 2] = v.z; ls[r][cc + 3] = v.w;
  }
  __syncthreads();
  int mc = (t & 7) * 8, nn = t >> 3;   // 8 lanes per output row, 16B/lane
#pragma unroll
  for (int i = 0; i < 2; ++i) {
    int n = nn + i * 32;
    uint4 q;
    q.x = f2bf(ls[mc][n])     | ((unsigned)f2bf(ls[mc + 1][n]) << 16);
    q.y = f2bf(ls[mc + 2][n]) | ((unsigned)f2bf(ls[mc + 3][n]) << 16);
    q.z = f2bf(ls[mc + 4][n]) | ((unsigned)f2bf(ls[mc + 5][n]) << 16);
    q.w = f2bf(ls[mc + 6][n]) | ((unsigned)f2bf(ls[mc + 7][n]) << 16);
    *reinterpret_cast<uint4*>(dst + (size_t)(n0 + n) * M + m0 + mc) = q;
  }
}

// -------------------------------------------------- fused gate+up GEMM ----
// LDS k-chunk XOR swizzle: logical 16B chunk q of row r lives at physical
// chunk q ^ ((r>>1)&3)  (row stride 64B = 16 banks -> 2-way max aliasing).
__global__ __launch_bounds__(256, 2) void gateup_kernel(
    const unsigned short* __restrict__ Xs, const unsigned short* __restrict__ wgT,
    const unsigned short* __restrict__ wuT, const int* __restrict__ hdr,
    const float* __restrict__ sw_g, unsigned short* __restrict__ Act) {
  int bx = blockIdx.x;                 // m-tile (fast axis: weight panel stays hot)
  int e = hdr[bx];
  if (e < 0) return;
  int row0 = hdr[64 + bx];
  int rowlim = hdr[128 + bx] - row0;
  int n0 = blockIdx.y * BN2;

  __shared__ __align__(16) unsigned short As[BM * BK2];
  __shared__ __align__(16) unsigned short Bg[BN2 * BK2];
  __shared__ __align__(16) unsigned short Bu[BN2 * BK2];
  __shared__ float sw[BM];

  int tid = threadIdx.x, lane = tid & 63, wave = tid >> 6;
  if (tid < BM) sw[tid] = sw_g[row0 + tid];

  const unsigned short* wgb = wgT + (size_t)e * IDIM * HDIM;  // [I][H] bf16
  const unsigned short* wub = wuT + (size_t)e * IDIM * HDIM;

  floatx4 accg[4][4], accu[4][4];
  floatx4 zz = {0.f, 0.f, 0.f, 0.f};
#pragma unroll
  for (int a = 0; a < 4; ++a)
#pragma unroll
    for (int b = 0; b < 4; ++b) { accg[a][b] = zz; accu[a][b] = zz; }

  int wm = (wave >> 1) * 64, wn = (wave & 1) * 64;
  int lr = lane >> 2;                        // row within 16-row chunk
  int lk = (((lane & 3) ^ ((lr >> 1) & 3)) * 8);   // swizzled global k-chunk
  int fr = lane & 15;
  int fq = (((lane >> 4) ^ ((fr >> 1) & 3)) * 8);  // swizzled read offset

  for (int kb = 0; kb < HDIM; kb += BK2) {
#pragma unroll
    for (int it = 0; it < 2; ++it) {
      int c = wave * 2 + it;     // 0..7, 16 rows each
      glds16(Xs  + (size_t)(row0 + c * 16 + lr) * HDIM + kb + lk, &As[c * 512]);
      glds16(wgb + (size_t)(n0  + c * 16 + lr) * HDIM + kb + lk, &Bg[c * 512]);
      glds16(wub + (size_t)(n0  + c * 16 + lr) * HDIM + kb + lk, &Bu[c * 512]);
    }
    __syncthreads();

    short8 af[4], bg8[4], bu8[4];
#pragma unroll
    for (int x = 0; x < 4; ++x) {
      af[x]  = *reinterpret_cast<const short8*>(&As[(wm + x * 16 + fr) * BK2 + fq]);
      bg8[x] = *reinterpret_cast<const short8*>(&Bg[(wn + x * 16 + fr) * BK2 + fq]);
      bu8[x] = *reinterpret_cast<const short8*>(&Bu[(wn + x * 16 + fr) * BK2 + fq]);
    }
#pragma unroll
    for (int tm = 0; tm < 4; ++tm)
#pragma unroll
      for (int tn = 0; tn < 4; ++tn) {
        accg[tm][tn] = __builtin_amdgcn_mfma_f32_16x16x32_bf16(af[tm], bg8[tn], accg[tm][tn], 0, 0, 0);
        accu[tm][tn] = __builtin_amdgcn_mfma_f32_16x16x32_bf16(af[tm], bu8[tn], accu[tm][tn], 0, 0, 0);
      }
    __syncthreads();
  }

#pragma unroll
  for (int tm = 0; tm < 4; ++tm)
#pragma unroll
    for (int tn = 0; tn < 4; ++tn)
#pragma unroll
      for (int r = 0; r < 4; ++r) {
        int rl = wm + tm * 16 + (lane >> 4) * 4 + r;
        if (rl < rowlim) {
          int col = n0 + wn + tn * 16 + fr;
          float g = accg[tm][tn][r];
          float u = accu[tm][tn][r];
          float s = g / (1.f + __expf(-g));
          Act[(size_t)(row0 + rl) * IDIM + col] = f2bf(s * u * sw[rl]);
        }
      }
}

// ------------------------------------------------------------ down GEMM ----
// Row stride 128B = 32 banks: without swizzle every row aliases (16-way!).
// Swizzle: logical 16B chunk q of row r at physical q ^ (r&7).
__global__ __launch_bounds__(256, 3) void down_kernel(
    const unsigned short* __restrict__ Act, const unsigned short* __restrict__ wdT,
    const int* __restrict__ hdr, const int* __restrict__ stok,
    float* __restrict__ out) {
  int bx = blockIdx.x;                 // m-tile fast
  int e = hdr[bx];
  if (e < 0) return;
  int row0 = hdr[64 + bx];
  int rowlim = hdr[128 + bx] - row0;
  int n0 = blockIdx.y * BN3;

  __shared__ __align__(16) unsigned short As[BM * BK3];   // 128 x 64
  __shared__ __align__(16) unsigned short Bd[BN3 * BK3];  // 64 x 64
  __shared__ int stk[BM];

  int tid = threadIdx.x, lane = tid & 63, wave = tid >> 6;
  if (tid < BM) stk[tid] = stok[row0 + tid];

  const unsigned short* wdb = wdT + (size_t)e * HDIM * IDIM;  // [H][I] bf16

  floatx4 acc[4][2];
  floatx4 zz = {0.f, 0.f, 0.f, 0.f};
#pragma unroll
  for (int a = 0; a < 4; ++a) { acc[a][0] = zz; acc[a][1] = zz; }

  int wm = (wave >> 1) * 64, wn = (wave & 1) * 32;
  int lr8 = lane >> 3;                         // row within 8-row chunk
  int lk8 = (((lane & 7) ^ lr8) * 8);          // swizzled global k-chunk
  int fr = lane & 15;
  int fk = fr & 7;                             // swizzle key on read

  for (int kb = 0; kb < IDIM; kb += BK3) {   // 44 iters
#pragma unroll
    for (int it = 0; it < 4; ++it) {
      int c = wave * 4 + it;     // 0..15, 8 rows each
      glds16(Act + (size_t)(row0 + c * 8 + lr8) * IDIM + kb + lk8, &As[c * 512]);
    }
#pragma unroll
    for (int it = 0; it < 2; ++it) {
      int c = wave * 2 + it;     // 0..7, 8 rows each
      glds16(wdb + (size_t)(n0 + c * 8 + lr8) * IDIM + kb + lk8, &Bd[c * 512]);
    }
    __syncthreads();

#pragma unroll
    for (int ks = 0; ks < BK3; ks += 32) {
      int q8 = (ks >> 3) + (lane >> 4);        // logical chunk 0..7
      int fo = ((q8 ^ fk) * 8);                // physical offset
      short8 af[4], bd8[2];
#pragma unroll
      for (int x = 0; x < 4; ++x)
        af[x] = *reinterpret_cast<const short8*>(&As[(wm + x * 16 + fr) * BK3 + fo]);
#pragma unroll
      for (int x = 0; x < 2; ++x)
        bd8[x] = *reinterpret_cast<const short8*>(&Bd[(wn + x * 16 + fr) * BK3 + fo]);
#pragma unroll
      for (int tm = 0; tm < 4; ++tm)
#pragma unroll
        for (int tn = 0; tn < 2; ++tn)
          acc[tm][tn] = __builtin_amdgcn_mfma_f32_16x16x32_bf16(af[tm], bd8[tn], acc[tm][tn], 0, 0, 0);
    }
    __syncthreads();
  }

#pragma unroll
  for (int tm = 0; tm < 4; ++tm)
#pragma unroll
    for (int tn = 0; tn < 2; ++tn)
#pragma unroll
      for (int r = 0; r < 4; ++r) {
        int rl = wm + tm * 16 + (lane >> 4) * 4 + r;
        if (rl < rowlim) {
          int col = n0 + wn + tn * 16 + fr;
          unsafeAtomicAdd(&out[(size_t)stk[rl] * HDIM + col], acc[tm][tn][r]);
        }
      }
}

// ======================== round-1 fallback kernels =========================
__global__ __launch_bounds__(512, 2) void gateup_fb(
    const unsigned short* __restrict__ Xs, const float* __restrict__ wg,
    const float* __restrict__ wu, const int* __restrict__ hdr,
    const float* __restrict__ sw_g, unsigned short* __restrict__ Act) {
  int by = blockIdx.y;
  int e = hdr[by];
  if (e < 0) return;
  int row0 = hdr[64 + by];
  int row_end = hdr[128 + by];
  int n0 = blockIdx.x * R1BN2;

  __shared__ __align__(16) unsigned short As[R1BM * R1BKp2];
  __shared__ __align__(16) unsigned short Bg[R1BN2 * R1BKp2];
  __shared__ __align__(16) unsigned short Bu[R1BN2 * R1BKp2];
  __shared__ float sw[R1BM];

  int tid = threadIdx.x, lane = tid & 63, wave = tid >> 6;
  if (tid < R1BM) sw[tid] = sw_g[row0 + tid];

  const float* wgb = wg + (size_t)e * HDIM * IDIM;
  const float* wub = wu + (size_t)e * HDIM * IDIM;

  floatx4 accg[4][4], accu[4][4];
  floatx4 zz = {0.f, 0.f, 0.f, 0.f};
#pragma unroll
  for (int a = 0; a < 4; ++a)
#pragma unroll
    for (int b = 0; b < 4; ++b) { accg[a][b] = zz; accu[a][b] = zz; }

  int wm = (wave >> 1) * 64, wn = (wave & 1) * 64;

  for (int kb = 0; kb < HDIM; kb += R1BK2) {
    __syncthreads();
#pragma unroll
    for (int it = 0; it < 2; ++it) {
      int cc = wave * 2 + it;
      int m = cc * 16 + (lane >> 2);
      int k = (lane & 3) * 8;
      uint4 v = *reinterpret_cast<const uint4*>(Xs + (size_t)(row0 + m) * HDIM + kb + k);
      *reinterpret_cast<uint4*>(&As[m * R1BKp2 + k]) = v;
    }
#pragma unroll
    for (int it = 0; it < 2; ++it) {
      int cc = wave * 2 + it;
      const float* wb = (cc & 8) ? wub : wgb;
      unsigned short* Bs = (cc & 8) ? Bu : Bg;
      int r = cc & 7;
      int kblk = r >> 1, nh = r & 1;
      int n = nh * 64 + lane;
      int k = kblk * 8;
      const float* src = wb + (size_t)(kb + k) * IDIM + n0 + n;
      uint4 q;
      q.x = f2bf(src[0])                | ((unsigned)f2bf(src[(size_t)IDIM])     << 16);
      q.y = f2bf(src[2 * (size_t)IDIM]) | ((unsigned)f2bf(src[3 * (size_t)IDIM]) << 16);
      q.z = f2bf(src[4 * (size_t)IDIM]) | ((unsigned)f2bf(src[5 * (size_t)IDIM]) << 16);
      q.w = f2bf(src[6 * (size_t)IDIM]) | ((unsigned)f2bf(src[7 * (size_t)IDIM]) << 16);
      *reinterpret_cast<uint4*>(&Bs[n * R1BKp2 + k]) = q;
    }
    __syncthreads();

    int krd = (lane >> 4) * 8;
    short8 af[4], bgf[4], buf_[4];
#pragma unroll
    for (int tm = 0; tm < 4; ++tm)
      af[tm] = *reinterpret_cast<const short8*>(&As[(wm + tm * 16 + (lane & 15)) * R1BKp2 + krd]);
#pragma unroll
    for (int tn = 0; tn < 4; ++tn) {
      bgf[tn]  = *reinterpret_cast<const short8*>(&Bg[(wn + tn * 16 + (lane & 15)) * R1BKp2 + krd]);
      buf_[tn] = *reinterpret_cast<const short8*>(&Bu[(wn + tn * 16 + (lane & 15)) * R1BKp2 + krd]);
    }
#pragma unroll
    for (int tm = 0; tm < 4; ++tm)
#pragma unroll
      for (int tn = 0; tn < 4; ++tn) {
        accg[tm][tn] = __builtin_amdgcn_mfma_f32_16x16x32_bf16(af[tm], bgf[tn], accg[tm][tn], 0, 0, 0);
        accu[tm][tn] = __builtin_amdgcn_mfma_f32_16x16x32_bf16(af[tm], buf_[tn], accu[tm][tn], 0, 0, 0);
      }
  }

  int rowlim = row_end - row0;
#pragma unroll
  for (int tm = 0; tm < 4; ++tm)
#pragma unroll
    for (int tn = 0; tn < 4; ++tn)
#pragma unroll
      for (int r = 0; r < 4; ++r) {
        int rl = wm + tm * 16 + (lane >> 4) * 4 + r;
        if (rl < rowlim) {
          int col = n0 + wn + tn * 16 + (lane & 15);
          float g = accg[tm][tn][r];
          float u = accu[tm][tn][r];
          float s = g / (1.f + __expf(-g));
          Act[(size_t)(row0 + rl) * IDIM + col] = f2bf(s * u * sw[rl]);
        }
      }
}

__global__ __launch_bounds__(512, 2) void down_fb(
    const unsigned short* __restrict__ Act, const float* __restrict__ wd,
    const int* __restrict__ hdr, const int* __restrict__ stok,
    float* __restrict__ out) {
  int by = blockIdx.y;
  int e = hdr[by];
  if (e < 0) return;
  int row0 = hdr[64 + by];
  int row_end = hdr[128 + by];
  int n0 = blockIdx.x * R1BN3;

  __shared__ __align__(16) unsigned short As[R1BM * R1BKp3];
  __shared__ __align__(16) unsigned short Bd[R1BN3 * R1BKp3];
  __shared__ int stk[R1BM];

  int tid = threadIdx.x, lane = tid & 63, wave = tid >> 6;
  if (tid < R1BM) stk[tid] = stok[row0 + tid];

  const float* wdb = wd + (size_t)e * IDIM * HDIM;

  floatx4 acc[4][2];
  floatx4 zz = {0.f, 0.f, 0.f, 0.f};
#pragma unroll
  for (int a = 0; a < 4; ++a) { acc[a][0] = zz; acc[a][1] = zz; }

  int wm = (wave >> 1) * 64, wn = (wave & 1) * 32;

  for (int kb = 0; kb < IDIM; kb += R1BK3) {
    __syncthreads();
#pragma unroll
    for (int it = 0; it < 4; ++it) {
      int cc = wave * 4 + it;
      int m = cc * 8 + (lane >> 3);
      int k = (lane & 7) * 8;
      uint4 v = *reinterpret_cast<const uint4*>(Act + (size_t)(row0 + m) * IDIM + kb + k);
      *reinterpret_cast<uint4*>(&As[m * R1BKp3 + k]) = v;
    }
    {
      int n = lane;
      int k = wave * 8;
      const float* src = wdb + (size_t)(kb + k) * HDIM + n0 + n;
      uint4 q;
      q.x = f2bf(src[0])        | ((unsigned)f2bf(src[HDIM])     << 16);
      q.y = f2bf(src[2 * HDIM]) | ((unsigned)f2bf(src[3 * HDIM]) << 16);
      q.z = f2bf(src[4 * HDIM]) | ((unsigned)f2bf(src[5 * HDIM]) << 16);
      q.w = f2bf(src[6 * HDIM]) | ((unsigned)f2bf(src[7 * HDIM]) << 16);
      *reinterpret_cast<uint4*>(&Bd[n * R1BKp3 + k]) = q;
    }
    __syncthreads();

#pragma unroll
    for (int ks = 0; ks < R1BK3; ks += 32) {
      int krd = ks + (lane >> 4) * 8;
      short8 af[4], bdf[2];
#pragma unroll
      for (int tm = 0; tm < 4; ++tm)
        af[tm] = *reinterpret_cast<const short8*>(&As[(wm + tm * 16 + (lane & 15)) * R1BKp3 + krd]);
#pragma unroll
      for (int tn = 0; tn < 2; ++tn)
        bdf[tn] = *reinterpret_cast<const short8*>(&Bd[(wn + tn * 16 + (lane & 15)) * R1BKp3 + krd]);
#pragma unroll
      for (int tm = 0; tm < 4; ++tm)
#pragma unroll
        for (int tn = 0; tn < 2; ++tn)
          acc[tm][tn] = __builtin_amdgcn_mfma_f32_16x16x32_bf16(af[tm], bdf[tn], acc[tm][tn], 0, 0, 0);
    }
  }

  int rowlim = row_end - row0;
#pragma unroll
  for (int tm = 0; tm < 4; ++tm)
#pragma unroll
    for (int tn = 0; tn < 2; ++tn)
#pragma unroll
      for (int r = 0; r < 4; ++r) {
        int rl = wm + tm * 16 + (lane >> 4) * 4 + r;
        if (rl < rowlim) {
          int col = n0 + wn + tn * 16 + (lane & 15);
          unsafeAtomicAdd(&out[(size_t)stk[rl] * HDIM + col], acc[tm][tn][r]);
        }
      }
}

// ---------------------------------------------------------------- launch ----
extern "C" void kernel_launch(void* const* d_in, const int* in_sizes, int n_in,
                              void* d_out, int out_size, void* d_ws, size_t ws_size,
                              hipStream_t stream) {
  const float* hidden = (const float*)d_in[0];
  const int* idx = (const int*)d_in[1];
  const float* vals = (const float*)d_in[2];
  const float* wg = (const float*)d_in[3];
  const float* wu = (const float*)d_in[4];
  const float* wd = (const float*)d_in[5];
  float* out = (float*)d_out;
  char* ws = (char*)d_ws;

  hipMemsetAsync(d_out, 0, (size_t)out_size * sizeof(float), stream);

  const size_t OFF_STOK = 4096;
  const size_t OFF_SW   = OFF_STOK + (size_t)NPP * 4;
  const size_t OFF_XS   = 65536;
  const size_t OFF_ACT  = OFF_XS + (size_t)NPP * HDIM * 2;
  const size_t OFF_WG   = OFF_ACT + (size_t)NPP * IDIM * 2;
  const size_t WSZ      = (size_t)NEXP * HDIM * IDIM * 2;   // 46.1 MB each
  const size_t OFF_WU   = OFF_WG + WSZ;
  const size_t NEED     = OFF_WU + WSZ;  // wdT aliases wgT

  if (ws_size >= NEED) {
    int* hdr = (int*)ws;
    int* stok = (int*)(ws + OFF_STOK);
    float* sw = (float*)(ws + OFF_SW);
    unsigned short* Xs  = (unsigned short*)(ws + OFF_XS);
    unsigned short* Act = (unsigned short*)(ws + OFF_ACT);
    unsigned short* wgT = (unsigned short*)(ws + OFF_WG);
    unsigned short* wuT = (unsigned short*)(ws + OFF_WU);
    unsigned short* wdT = wgT;  // alias: wd converted after gateup consumed wgT

    setup_kernel<<<1, 256, 0, stream>>>(idx, vals, hdr, stok, sw, BM);
    convert_kernel<<<dim3(704, NEXP, 2), 256, 0, stream>>>(wg, wu, wd, wgT, wuT, wdT, 0);
    gather_kernel<<<NPAIR, 256, 0, stream>>>(hidden, stok, Xs);
    gateup_kernel<<<dim3(MAX_TILES, IDIM / BN2), 256, 0, stream>>>(Xs, wgT, wuT, hdr, sw, Act);
    convert_kernel<<<dim3(704, NEXP, 1), 256, 0, stream>>>(wg, wu, wd, wgT, wuT, wdT, 2);
    down_kernel<<<dim3(MAX_TILES, HDIM / BN3), 256, 0, stream>>>(Act, wdT, hdr, stok, out);
  } else {
    int* hdr = (int*)ws;
    int* stok = (int*)(ws + 4096);
    float* sw = (float*)(ws + 4096 + (size_t)R1NPP * 4);
    unsigned short* Xs  = (unsigned short*)(ws + 65536);
    unsigned short* Act = (unsigned short*)(ws + 65536 + (size_t)R1NPP * HDIM * 2);

    setup_kernel<<<1, 256, 0, stream>>>(idx, vals, hdr, stok, sw, R1BM);
    gather_kernel<<<NPAIR, 256, 0, stream>>>(hidden, stok, Xs);
    gateup_fb<<<dim3(IDIM / R1BN2, R1T), 512, 0, stream>>>(Xs, wg, wu, hdr, sw, Act);
    down_fb<<<dim3(HDIM / R1BN3, R1T), 512, 0, stream>>>(Act, wd, hdr, stok, out);
  }
}